// Round 1
// baseline (681.941 us; speedup 1.0000x reference)
//
#include <hip/hip_runtime.h>
#include <hip/hip_bf16.h>

typedef __hip_bfloat16 bf16;
typedef __bf16 bf16x8 __attribute__((ext_vector_type(8)));
typedef float f32x4 __attribute__((ext_vector_type(4)));

#define DEV __device__ __forceinline__

DEV int swz(int r, int k) { return r * 64 + (k ^ ((r & 7) << 3)); }

// ---------------- weight transpose + f32->bf16 ----------------
// W [K][N] f32  ->  WT [N][K] bf16
__global__ void transpose_cvt(const float* __restrict__ W, bf16* __restrict__ WT,
                              int K, int N) {
  __shared__ bf16 t[32][33];
  int bx = blockIdx.x * 32, by = blockIdx.y * 32;
  int tx = threadIdx.x, ty = threadIdx.y;
#pragma unroll
  for (int j = 0; j < 32; j += 8)
    t[ty + j][tx] = __float2bfloat16(W[(size_t)(by + ty + j) * N + bx + tx]);
  __syncthreads();
#pragma unroll
  for (int j = 0; j < 32; j += 8)
    WT[(size_t)(bx + ty + j) * K + by + tx] = t[tx][ty + j];
}

// ---------------- LN1: x = LN(input); store f32 + bf16 ----------------
__global__ __launch_bounds__(256) void ln1_kernel(
    const float* __restrict__ in, const float* __restrict__ g, const float* __restrict__ b,
    float* __restrict__ xo, bf16* __restrict__ xb) {
  int row = blockIdx.x, tid = threadIdx.x;
  int lane = tid & 63, w = tid >> 6;
  float4 v = reinterpret_cast<const float4*>(in + (size_t)row * 1024)[tid];
  float s = v.x + v.y + v.z + v.w;
  float sq = v.x * v.x + v.y * v.y + v.z * v.z + v.w * v.w;
#pragma unroll
  for (int m = 32; m; m >>= 1) { s += __shfl_xor(s, m); sq += __shfl_xor(sq, m); }
  __shared__ float ss[4], qq[4];
  if (lane == 0) { ss[w] = s; qq[w] = sq; }
  __syncthreads();
  s = ss[0] + ss[1] + ss[2] + ss[3];
  sq = qq[0] + qq[1] + qq[2] + qq[3];
  float mu = s * (1.f / 1024.f);
  float rs = rsqrtf(sq * (1.f / 1024.f) - mu * mu + 1e-5f);
  float4 gg = reinterpret_cast<const float4*>(g)[tid];
  float4 bb = reinterpret_cast<const float4*>(b)[tid];
  float4 y;
  y.x = (v.x - mu) * rs * gg.x + bb.x;
  y.y = (v.y - mu) * rs * gg.y + bb.y;
  y.z = (v.z - mu) * rs * gg.z + bb.z;
  y.w = (v.w - mu) * rs * gg.w + bb.w;
  reinterpret_cast<float4*>(xo + (size_t)row * 1024)[tid] = y;
  union { bf16 h[4]; uint2 u; } pk;
  pk.h[0] = __float2bfloat16(y.x); pk.h[1] = __float2bfloat16(y.y);
  pk.h[2] = __float2bfloat16(y.z); pk.h[3] = __float2bfloat16(y.w);
  reinterpret_cast<uint2*>(xb + (size_t)row * 1024)[tid] = pk.u;
}

// ------- LN23: x2 = x + LN2(ao) (f32 out); h = LN3(x2) (bf16 out) -------
__global__ __launch_bounds__(256) void ln23_kernel(
    const float* __restrict__ x, const float* __restrict__ ao,
    const float* __restrict__ g2, const float* __restrict__ b2,
    const float* __restrict__ g3, const float* __restrict__ b3,
    float* __restrict__ x2o, bf16* __restrict__ hb) {
  int row = blockIdx.x, tid = threadIdx.x;
  int lane = tid & 63, w = tid >> 6;
  float4 a = reinterpret_cast<const float4*>(ao + (size_t)row * 1024)[tid];
  float s = a.x + a.y + a.z + a.w;
  float sq = a.x * a.x + a.y * a.y + a.z * a.z + a.w * a.w;
#pragma unroll
  for (int m = 32; m; m >>= 1) { s += __shfl_xor(s, m); sq += __shfl_xor(sq, m); }
  __shared__ float s1[4], q1[4], s2[4], q2[4];
  if (lane == 0) { s1[w] = s; q1[w] = sq; }
  __syncthreads();
  s = s1[0] + s1[1] + s1[2] + s1[3];
  sq = q1[0] + q1[1] + q1[2] + q1[3];
  float mu = s * (1.f / 1024.f);
  float rs = rsqrtf(sq * (1.f / 1024.f) - mu * mu + 1e-5f);
  float4 xr = reinterpret_cast<const float4*>(x + (size_t)row * 1024)[tid];
  float4 gg = reinterpret_cast<const float4*>(g2)[tid];
  float4 bb = reinterpret_cast<const float4*>(b2)[tid];
  float4 x2;
  x2.x = xr.x + (a.x - mu) * rs * gg.x + bb.x;
  x2.y = xr.y + (a.y - mu) * rs * gg.y + bb.y;
  x2.z = xr.z + (a.z - mu) * rs * gg.z + bb.z;
  x2.w = xr.w + (a.w - mu) * rs * gg.w + bb.w;
  reinterpret_cast<float4*>(x2o + (size_t)row * 1024)[tid] = x2;
  // phase 2: LN3 over x2
  s = x2.x + x2.y + x2.z + x2.w;
  sq = x2.x * x2.x + x2.y * x2.y + x2.z * x2.z + x2.w * x2.w;
#pragma unroll
  for (int m = 32; m; m >>= 1) { s += __shfl_xor(s, m); sq += __shfl_xor(sq, m); }
  if (lane == 0) { s2[w] = s; q2[w] = sq; }
  __syncthreads();
  s = s2[0] + s2[1] + s2[2] + s2[3];
  sq = q2[0] + q2[1] + q2[2] + q2[3];
  mu = s * (1.f / 1024.f);
  rs = rsqrtf(sq * (1.f / 1024.f) - mu * mu + 1e-5f);
  gg = reinterpret_cast<const float4*>(g3)[tid];
  bb = reinterpret_cast<const float4*>(b3)[tid];
  union { bf16 h[4]; uint2 u; } pk;
  pk.h[0] = __float2bfloat16((x2.x - mu) * rs * gg.x + bb.x);
  pk.h[1] = __float2bfloat16((x2.y - mu) * rs * gg.y + bb.y);
  pk.h[2] = __float2bfloat16((x2.z - mu) * rs * gg.z + bb.z);
  pk.h[3] = __float2bfloat16((x2.w - mu) * rs * gg.w + bb.w);
  reinterpret_cast<uint2*>(hb + (size_t)row * 1024)[tid] = pk.u;
}

// ---------------- GEMM: C[M,N] = A[M,K] @ BT[N,K]^T + bias ----------------
// A, BT bf16 row-major. Optional GELU / residual / bf16-vs-f32 output.
template <bool GELU, bool RES, bool OUTBF>
__global__ __launch_bounds__(256, 2) void gemm_bt(
    const bf16* __restrict__ A, const bf16* __restrict__ BT,
    const float* __restrict__ bias, const float* __restrict__ res,
    float* __restrict__ outf, bf16* __restrict__ outb,
    int M, int N, int K) {
  __shared__ __align__(16) bf16 As[128 * 64];
  __shared__ __align__(16) bf16 Bs[128 * 64];
  const int t = threadIdx.x;
  const int lane = t & 63, w = t >> 6;
  const int wr = w >> 1, wc = w & 1;
  const int m0 = blockIdx.y * 128, n0 = blockIdx.x * 128;
  const int l15 = lane & 15, l4 = lane >> 4;
  const int srow = t >> 3;         // 0..31
  const int sk = (t & 7) * 8;      // 0..56

  f32x4 acc[4][4] = {};

  const int nk = K >> 6;
  for (int kt = 0; kt < nk; ++kt) {
    const int k0 = kt << 6;
    uint4 ar[4], br[4];
#pragma unroll
    for (int p = 0; p < 4; ++p) {
      int r = p * 32 + srow;
      ar[p] = *reinterpret_cast<const uint4*>(A + (size_t)(m0 + r) * K + k0 + sk);
      br[p] = *reinterpret_cast<const uint4*>(BT + (size_t)(n0 + r) * K + k0 + sk);
    }
    __syncthreads();
#pragma unroll
    for (int p = 0; p < 4; ++p) {
      int r = p * 32 + srow;
      *reinterpret_cast<uint4*>(&As[swz(r, sk)]) = ar[p];
      *reinterpret_cast<uint4*>(&Bs[swz(r, sk)]) = br[p];
    }
    __syncthreads();
#pragma unroll
    for (int ks = 0; ks < 2; ++ks) {
      bf16x8 af[4], bfr[4];
#pragma unroll
      for (int m = 0; m < 4; ++m)
        af[m] = *reinterpret_cast<const bf16x8*>(&As[swz(wr * 64 + m * 16 + l15, ks * 32 + l4 * 8)]);
#pragma unroll
      for (int n = 0; n < 4; ++n)
        bfr[n] = *reinterpret_cast<const bf16x8*>(&Bs[swz(wc * 64 + n * 16 + l15, ks * 32 + l4 * 8)]);
#pragma unroll
      for (int m = 0; m < 4; ++m)
#pragma unroll
        for (int n = 0; n < 4; ++n)
          acc[m][n] = __builtin_amdgcn_mfma_f32_16x16x32_bf16(af[m], bfr[n], acc[m][n], 0, 0, 0);
    }
  }
  // epilogue: D row = (lane>>4)*4 + reg, col = lane&15 (m89-verified layout)
#pragma unroll
  for (int m = 0; m < 4; ++m) {
    int gr0 = m0 + wr * 64 + m * 16 + l4 * 4;
#pragma unroll
    for (int n = 0; n < 4; ++n) {
      int gc = n0 + wc * 64 + n * 16 + l15;
      float bv = bias[gc];
#pragma unroll
      for (int q = 0; q < 4; ++q) {
        int gr = gr0 + q;
        float v = acc[m][n][q] + bv;
        if constexpr (GELU) v = 0.5f * v * (1.f + erff(v * 0.70710678118654752f));
        if constexpr (RES) v += res[(size_t)gr * N + gc];
        if constexpr (OUTBF) outb[(size_t)gr * N + gc] = __float2bfloat16(v);
        else                 outf[(size_t)gr * N + gc] = v;
      }
    }
  }
}

// ---------------- flash attention ----------------
// grid (S/64, H, B); 4 waves, each owns 16 q-rows. K/V tiles of 32 keys in LDS.
__global__ __launch_bounds__(256, 2) void attn_kernel(
    const bf16* __restrict__ q, const bf16* __restrict__ k,
    const bf16* __restrict__ v, bf16* __restrict__ o) {
  const int S = 1024, HD = 1024, KPAD = 960;
  const int qt = blockIdx.x, h = blockIdx.y, b = blockIdx.z;
  const int t = threadIdx.x, lane = t & 63, w = t >> 6;
  const int l15 = lane & 15, l4 = lane >> 4;
  const int q0 = qt * 64;
  const int qw = q0 + w * 16;

  __shared__ __align__(16) bf16 Ks[32 * 64];
  __shared__ __align__(16) bf16 VT[64 * 32];
  __shared__ __align__(16) bf16 P[4][16 * 32];

  bf16x8 qf[2];
  {
    const bf16* qp = q + (size_t)(b * S + qw + l15) * HD + h * 64 + l4 * 8;
    qf[0] = *reinterpret_cast<const bf16x8*>(qp);
    qf[1] = *reinterpret_cast<const bf16x8*>(qp + 32);
  }

  f32x4 acc[4] = {};
  float mrow[4], lrow[4];
#pragma unroll
  for (int i = 0; i < 4; ++i) { mrow[i] = -1e30f; lrow[i] = 0.f; }

  const int kmaxa = q0 + 63, kmaxb = S - 65;
  const int kmax = kmaxa < kmaxb ? kmaxa : kmaxb;
  const int nt = (kmax >> 5) + 1;
  const int skey = t >> 3, sd = (t & 7) * 8;

  for (int kt = 0; kt < nt; ++kt) {
    const int kb = kt * 32;
    uint4 kv = *reinterpret_cast<const uint4*>(k + (size_t)(b * S + kb + skey) * HD + h * 64 + sd);
    uint4 vv = *reinterpret_cast<const uint4*>(v + (size_t)(b * S + kb + skey) * HD + h * 64 + sd);
    __syncthreads();
    *reinterpret_cast<uint4*>(&Ks[swz(skey, sd)]) = kv;
    union { uint4 u; bf16 e[8]; } vu; vu.u = vv;
#pragma unroll
    for (int j = 0; j < 8; ++j) {
      int d = sd + j;
      VT[d * 32 + (skey ^ ((d & 3) << 3))] = vu.e[j];
    }
    __syncthreads();

    // scores S[16q x 32key]
    f32x4 sc[2];
#pragma unroll
    for (int cb = 0; cb < 2; ++cb) {
      int key = cb * 16 + l15;
      bf16x8 k0f = *reinterpret_cast<const bf16x8*>(&Ks[swz(key, l4 * 8)]);
      bf16x8 k1f = *reinterpret_cast<const bf16x8*>(&Ks[swz(key, 32 + l4 * 8)]);
      f32x4 z = {};
      z = __builtin_amdgcn_mfma_f32_16x16x32_bf16(qf[0], k0f, z, 0, 0, 0);
      z = __builtin_amdgcn_mfma_f32_16x16x32_bf16(qf[1], k1f, z, 0, 0, 0);
      sc[cb] = z;
    }
#pragma unroll
    for (int cb = 0; cb < 2; ++cb) {
      int key = kb + cb * 16 + l15;
#pragma unroll
      for (int r = 0; r < 4; ++r) {
        int qrow = qw + l4 * 4 + r;
        float sv = sc[cb][r] * 0.125f;
        if (key > qrow || key >= KPAD) sv = -1e30f;
        sc[cb][r] = sv;
      }
    }
    // online softmax (rows live in 16-lane groups)
    float pr0[4], pr1[4];
#pragma unroll
    for (int r = 0; r < 4; ++r) {
      float mt = fmaxf(sc[0][r], sc[1][r]);
#pragma unroll
      for (int m = 8; m >= 1; m >>= 1) mt = fmaxf(mt, __shfl_xor(mt, m));
      float mn = fmaxf(mrow[r], mt);
      float alpha = __expf(mrow[r] - mn);
      float p0 = __expf(sc[0][r] - mn), p1 = __expf(sc[1][r] - mn);
      float rsum = p0 + p1;
#pragma unroll
      for (int m = 8; m >= 1; m >>= 1) rsum += __shfl_xor(rsum, m);
      lrow[r] = lrow[r] * alpha + rsum;
      mrow[r] = mn;
      pr0[r] = p0; pr1[r] = p1;
#pragma unroll
      for (int n = 0; n < 4; ++n) acc[n][r] *= alpha;
    }
    // P -> per-wave LDS (D-layout write, A-layout read)
#pragma unroll
    for (int r = 0; r < 4; ++r) {
      int rr = l4 * 4 + r;
      int c0 = l15, c1 = 16 + l15;
      P[w][rr * 32 + (c0 ^ ((rr & 3) << 3))] = __float2bfloat16(pr0[r]);
      P[w][rr * 32 + (c1 ^ ((rr & 3) << 3))] = __float2bfloat16(pr1[r]);
    }
    asm volatile("" ::: "memory");  // forbid hoisting the cross-lane LDS read
    bf16x8 pf = *reinterpret_cast<const bf16x8*>(&P[w][l15 * 32 + ((l4 ^ (l15 & 3)) << 3)]);
#pragma unroll
    for (int n = 0; n < 4; ++n) {
      int col = n * 16 + l15;
      bf16x8 vf = *reinterpret_cast<const bf16x8*>(&VT[col * 32 + ((l4 ^ (col & 3)) << 3)]);
      acc[n] = __builtin_amdgcn_mfma_f32_16x16x32_bf16(pf, vf, acc[n], 0, 0, 0);
    }
  }
#pragma unroll
  for (int r = 0; r < 4; ++r) {
    float inv = 1.f / lrow[r];
    int qrow = qw + l4 * 4 + r;
#pragma unroll
    for (int n = 0; n < 4; ++n)
      o[(size_t)(b * S + qrow) * HD + h * 64 + n * 16 + l15] = __float2bfloat16(acc[n][r] * inv);
  }
}

// ---------------- launch ----------------
extern "C" void kernel_launch(void* const* d_in, const int* in_sizes, int n_in,
                              void* d_out, int out_size, void* d_ws, size_t ws_size,
                              hipStream_t stream) {
  const float* input = (const float*)d_in[0];
  const float* ln1g = (const float*)d_in[3];
  const float* ln1b = (const float*)d_in[4];
  const float* ln2g = (const float*)d_in[5];
  const float* ln2b = (const float*)d_in[6];
  const float* ln3g = (const float*)d_in[7];
  const float* ln3b = (const float*)d_in[8];
  const float* Wq = (const float*)d_in[9];  const float* bq = (const float*)d_in[10];
  const float* Wk = (const float*)d_in[11]; const float* bk = (const float*)d_in[12];
  const float* Wv = (const float*)d_in[13]; const float* bv = (const float*)d_in[14];
  const float* Wo = (const float*)d_in[15]; const float* bo = (const float*)d_in[16];
  const float* W1 = (const float*)d_in[17]; const float* b1 = (const float*)d_in[18];
  const float* W2 = (const float*)d_in[19]; const float* b2 = (const float*)d_in[20];

  const int M = 4096, D = 1024, F = 4096;
  char* p = (char*)d_ws;
  size_t off = 0;
  auto nxt = [&](size_t n) { char* r = p + off; off += n; return r; };
  bf16* WqT = (bf16*)nxt((size_t)D * D * 2);
  bf16* WkT = (bf16*)nxt((size_t)D * D * 2);
  bf16* WvT = (bf16*)nxt((size_t)D * D * 2);
  bf16* WoT = (bf16*)nxt((size_t)D * D * 2);
  bf16* W1T = (bf16*)nxt((size_t)F * D * 2);
  bf16* W2T = (bf16*)nxt((size_t)D * F * 2);
  float* xf  = (float*)nxt((size_t)M * D * 4);   // LN1 out (f32)
  float* aof = (float*)nxt((size_t)M * D * 4);   // attn proj out (f32)
  float* x2f = (float*)nxt((size_t)M * D * 4);   // x2 (f32)
  bf16* xb = (bf16*)nxt((size_t)M * D * 2);      // LN1 out bf16; reused as attn out
  bf16* qb = (bf16*)nxt((size_t)M * D * 2);      // q; reused as h
  bf16* kb = (bf16*)nxt((size_t)M * D * 2);
  bf16* vb = (bf16*)nxt((size_t)M * D * 2);
  bf16* gb = (bf16*)xf;   // gelu out [4096,4096] bf16 overlays xf+aof (dead by then)
  bf16* ab = xb;
  bf16* hb = qb;

  dim3 tb(32, 8);
  transpose_cvt<<<dim3(D / 32, D / 32), tb, 0, stream>>>(Wq, WqT, D, D);
  transpose_cvt<<<dim3(D / 32, D / 32), tb, 0, stream>>>(Wk, WkT, D, D);
  transpose_cvt<<<dim3(D / 32, D / 32), tb, 0, stream>>>(Wv, WvT, D, D);
  transpose_cvt<<<dim3(D / 32, D / 32), tb, 0, stream>>>(Wo, WoT, D, D);
  transpose_cvt<<<dim3(F / 32, D / 32), tb, 0, stream>>>(W1, W1T, D, F);
  transpose_cvt<<<dim3(D / 32, F / 32), tb, 0, stream>>>(W2, W2T, F, D);

  ln1_kernel<<<M, 256, 0, stream>>>(input, ln1g, ln1b, xf, xb);

  gemm_bt<false, false, true><<<dim3(D / 128, M / 128), 256, 0, stream>>>(
      xb, WqT, bq, nullptr, nullptr, qb, M, D, D);
  gemm_bt<false, false, true><<<dim3(D / 128, M / 128), 256, 0, stream>>>(
      xb, WkT, bk, nullptr, nullptr, kb, M, D, D);
  gemm_bt<false, false, true><<<dim3(D / 128, M / 128), 256, 0, stream>>>(
      xb, WvT, bv, nullptr, nullptr, vb, M, D, D);

  attn_kernel<<<dim3(16, 16, 4), 256, 0, stream>>>(qb, kb, vb, ab);

  gemm_bt<false, false, false><<<dim3(D / 128, M / 128), 256, 0, stream>>>(
      ab, WoT, bo, nullptr, aof, nullptr, M, D, D);

  ln23_kernel<<<M, 256, 0, stream>>>(xf, aof, ln2g, ln2b, ln3g, ln3b, x2f, hb);

  gemm_bt<true, false, true><<<dim3(F / 128, M / 128), 256, 0, stream>>>(
      hb, W1T, b1, nullptr, nullptr, gb, M, F, D);
  gemm_bt<false, true, false><<<dim3(D / 128, M / 128), 256, 0, stream>>>(
      gb, W2T, b2, x2f, (float*)d_out, nullptr, M, D, F);
}

// Round 2
// 337.547 us; speedup vs baseline: 2.0203x; 2.0203x over previous
//
#include <hip/hip_runtime.h>
#include <hip/hip_bf16.h>

typedef __hip_bfloat16 bf16;
typedef __bf16 bf16x8 __attribute__((ext_vector_type(8)));
typedef float f32x4 __attribute__((ext_vector_type(4)));

#define DEV __device__ __forceinline__

DEV int swz(int r, int k) { return r * 64 + (k ^ ((r & 7) << 3)); }

#define GLOAD_LDS16(gaddr, laddr)                                              \
  __builtin_amdgcn_global_load_lds(                                            \
      (const __attribute__((address_space(1))) void*)(gaddr),                  \
      (__attribute__((address_space(3))) void*)(laddr), 16, 0, 0)

// ---------------- weight transpose + f32->bf16 ----------------
// W [K][N] f32  ->  WT [N][K] bf16
__global__ void transpose_cvt(const float* __restrict__ W, bf16* __restrict__ WT,
                              int K, int N) {
  __shared__ bf16 t[32][33];
  int bx = blockIdx.x * 32, by = blockIdx.y * 32;
  int tx = threadIdx.x, ty = threadIdx.y;
#pragma unroll
  for (int j = 0; j < 32; j += 8)
    t[ty + j][tx] = __float2bfloat16(W[(size_t)(by + ty + j) * N + bx + tx]);
  __syncthreads();
#pragma unroll
  for (int j = 0; j < 32; j += 8)
    WT[(size_t)(bx + ty + j) * K + by + tx] = t[tx][ty + j];
}

__global__ void concat3(const float* __restrict__ a, const float* __restrict__ b,
                        const float* __restrict__ c, float* __restrict__ o) {
  int i = blockIdx.x * 256 + threadIdx.x;
  if (i < 3072) o[i] = i < 1024 ? a[i] : (i < 2048 ? b[i - 1024] : c[i - 2048]);
}

// ---------------- LN1: x = LN(input); store f32 + bf16 ----------------
__global__ __launch_bounds__(256) void ln1_kernel(
    const float* __restrict__ in, const float* __restrict__ g, const float* __restrict__ b,
    float* __restrict__ xo, bf16* __restrict__ xb) {
  int row = blockIdx.x, tid = threadIdx.x;
  int lane = tid & 63, w = tid >> 6;
  float4 v = reinterpret_cast<const float4*>(in + (size_t)row * 1024)[tid];
  float s = v.x + v.y + v.z + v.w;
  float sq = v.x * v.x + v.y * v.y + v.z * v.z + v.w * v.w;
#pragma unroll
  for (int m = 32; m; m >>= 1) { s += __shfl_xor(s, m); sq += __shfl_xor(sq, m); }
  __shared__ float ss[4], qq[4];
  if (lane == 0) { ss[w] = s; qq[w] = sq; }
  __syncthreads();
  s = ss[0] + ss[1] + ss[2] + ss[3];
  sq = qq[0] + qq[1] + qq[2] + qq[3];
  float mu = s * (1.f / 1024.f);
  float rs = rsqrtf(sq * (1.f / 1024.f) - mu * mu + 1e-5f);
  float4 gg = reinterpret_cast<const float4*>(g)[tid];
  float4 bb = reinterpret_cast<const float4*>(b)[tid];
  float4 y;
  y.x = (v.x - mu) * rs * gg.x + bb.x;
  y.y = (v.y - mu) * rs * gg.y + bb.y;
  y.z = (v.z - mu) * rs * gg.z + bb.z;
  y.w = (v.w - mu) * rs * gg.w + bb.w;
  reinterpret_cast<float4*>(xo + (size_t)row * 1024)[tid] = y;
  union { bf16 h[4]; uint2 u; } pk;
  pk.h[0] = __float2bfloat16(y.x); pk.h[1] = __float2bfloat16(y.y);
  pk.h[2] = __float2bfloat16(y.z); pk.h[3] = __float2bfloat16(y.w);
  reinterpret_cast<uint2*>(xb + (size_t)row * 1024)[tid] = pk.u;
}

// ------- LN23: x2 = x + LN2(ao) (f32 out); h = LN3(x2) (bf16 out) -------
__global__ __launch_bounds__(256) void ln23_kernel(
    const float* __restrict__ x, const float* __restrict__ ao,
    const float* __restrict__ g2, const float* __restrict__ b2,
    const float* __restrict__ g3, const float* __restrict__ b3,
    float* __restrict__ x2o, bf16* __restrict__ hb) {
  int row = blockIdx.x, tid = threadIdx.x;
  int lane = tid & 63, w = tid >> 6;
  float4 a = reinterpret_cast<const float4*>(ao + (size_t)row * 1024)[tid];
  float s = a.x + a.y + a.z + a.w;
  float sq = a.x * a.x + a.y * a.y + a.z * a.z + a.w * a.w;
#pragma unroll
  for (int m = 32; m; m >>= 1) { s += __shfl_xor(s, m); sq += __shfl_xor(sq, m); }
  __shared__ float s1[4], q1[4], s2[4], q2[4];
  if (lane == 0) { s1[w] = s; q1[w] = sq; }
  __syncthreads();
  s = s1[0] + s1[1] + s1[2] + s1[3];
  sq = q1[0] + q1[1] + q1[2] + q1[3];
  float mu = s * (1.f / 1024.f);
  float rs = rsqrtf(sq * (1.f / 1024.f) - mu * mu + 1e-5f);
  float4 xr = reinterpret_cast<const float4*>(x + (size_t)row * 1024)[tid];
  float4 gg = reinterpret_cast<const float4*>(g2)[tid];
  float4 bb = reinterpret_cast<const float4*>(b2)[tid];
  float4 x2;
  x2.x = xr.x + (a.x - mu) * rs * gg.x + bb.x;
  x2.y = xr.y + (a.y - mu) * rs * gg.y + bb.y;
  x2.z = xr.z + (a.z - mu) * rs * gg.z + bb.z;
  x2.w = xr.w + (a.w - mu) * rs * gg.w + bb.w;
  reinterpret_cast<float4*>(x2o + (size_t)row * 1024)[tid] = x2;
  s = x2.x + x2.y + x2.z + x2.w;
  sq = x2.x * x2.x + x2.y * x2.y + x2.z * x2.z + x2.w * x2.w;
#pragma unroll
  for (int m = 32; m; m >>= 1) { s += __shfl_xor(s, m); sq += __shfl_xor(sq, m); }
  if (lane == 0) { s2[w] = s; q2[w] = sq; }
  __syncthreads();
  s = s2[0] + s2[1] + s2[2] + s2[3];
  sq = q2[0] + q2[1] + q2[2] + q2[3];
  mu = s * (1.f / 1024.f);
  rs = rsqrtf(sq * (1.f / 1024.f) - mu * mu + 1e-5f);
  gg = reinterpret_cast<const float4*>(g3)[tid];
  bb = reinterpret_cast<const float4*>(b3)[tid];
  union { bf16 h[4]; uint2 u; } pk;
  pk.h[0] = __float2bfloat16((x2.x - mu) * rs * gg.x + bb.x);
  pk.h[1] = __float2bfloat16((x2.y - mu) * rs * gg.y + bb.y);
  pk.h[2] = __float2bfloat16((x2.z - mu) * rs * gg.z + bb.z);
  pk.h[3] = __float2bfloat16((x2.w - mu) * rs * gg.w + bb.w);
  reinterpret_cast<uint2*>(hb + (size_t)row * 1024)[tid] = pk.u;
}

// ---------------- GEMM: C[M,N] = A[M,K] @ BT[N,K]^T + bias ----------------
// m97 structure: global_load_lds width-16 staging (linear LDS dest,
// pre-swizzled global source), 2-barrier K-loop, swizzled ds_read_b128.
template <int BN, int NT, bool GELU, bool RES, bool OUTBF>
__global__ __launch_bounds__(256, 4) void gemm_bt(
    const bf16* __restrict__ A, const bf16* __restrict__ BT,
    const float* __restrict__ bias, const float* __restrict__ res,
    float* __restrict__ outf, bf16* __restrict__ outb,
    int M, int N, int K) {
  constexpr int BM = 128, BK = 64;
  constexpr int ACH = BM / 8;          // 1KB chunks in A tile
  constexpr int BCH = BN / 8;
  constexpr int PW = (ACH + BCH) / 4;  // chunks per wave
  constexpr int MT = 4;                // wave covers 64 rows (WR=2)
  __shared__ __align__(16) bf16 As[BM * BK];
  __shared__ __align__(16) bf16 Bs[BN * BK];
  const int t = threadIdx.x, lane = t & 63, w = t >> 6;
  const int wr = w >> 1, wc = w & 1;
  const int l15 = lane & 15, l4 = lane >> 4;
  // XCD-aware bijective swizzle (all grids have nwg % 8 == 0)
  const int gx = gridDim.x, nwg = gx * gridDim.y;
  int bid = blockIdx.y * gx + blockIdx.x;
  int sbid = (bid & 7) * (nwg >> 3) + (bid >> 3);
  const int m0 = (sbid / gx) * BM, n0 = (sbid % gx) * BN;
  const int lr = lane >> 3;            // chunk-local row 0..7
  const int lc = (lane & 7) * 8;       // chunk-local col (elements)
  const int scol = lc ^ (lr * 8);      // pre-swizzled source column

  f32x4 acc[MT][NT] = {};

  const int nk = K >> 6;
  for (int kt = 0; kt < nk; ++kt) {
    const int k0 = kt << 6;
    __syncthreads();  // all waves done reading LDS of previous tile
#pragma unroll
    for (int i = 0; i < PW; ++i) {
      int c = w * PW + i;
      if (c < ACH) {
        GLOAD_LDS16(A + (size_t)(m0 + c * 8 + lr) * K + k0 + scol, &As[c * 512]);
      } else {
        int c2 = c - ACH;
        GLOAD_LDS16(BT + (size_t)(n0 + c2 * 8 + lr) * K + k0 + scol, &Bs[c2 * 512]);
      }
    }
    __syncthreads();  // compiler drains vmcnt(0) before barrier -> tile landed
#pragma unroll
    for (int ks = 0; ks < 2; ++ks) {
      bf16x8 af[MT], bfr[NT];
#pragma unroll
      for (int m = 0; m < MT; ++m)
        af[m] = *reinterpret_cast<const bf16x8*>(&As[swz(wr * 64 + m * 16 + l15, ks * 32 + l4 * 8)]);
#pragma unroll
      for (int n = 0; n < NT; ++n)
        bfr[n] = *reinterpret_cast<const bf16x8*>(&Bs[swz(wc * (BN / 2) + n * 16 + l15, ks * 32 + l4 * 8)]);
#pragma unroll
      for (int m = 0; m < MT; ++m)
#pragma unroll
        for (int n = 0; n < NT; ++n)
          acc[m][n] = __builtin_amdgcn_mfma_f32_16x16x32_bf16(af[m], bfr[n], acc[m][n], 0, 0, 0);
    }
  }
  // epilogue: D row = (lane>>4)*4 + reg, col = lane&15
#pragma unroll
  for (int m = 0; m < MT; ++m) {
    int gr0 = m0 + wr * 64 + m * 16 + l4 * 4;
#pragma unroll
    for (int n = 0; n < NT; ++n) {
      int gc = n0 + wc * (BN / 2) + n * 16 + l15;
      float bv = bias[gc];
#pragma unroll
      for (int q = 0; q < 4; ++q) {
        int gr = gr0 + q;
        float v = acc[m][n][q] + bv;
        if constexpr (GELU) v = 0.5f * v * (1.f + erff(v * 0.70710678118654752f));
        if constexpr (RES) v += res[(size_t)gr * N + gc];
        if constexpr (OUTBF) outb[(size_t)gr * N + gc] = __float2bfloat16(v);
        else                 outf[(size_t)gr * N + gc] = v;
      }
    }
  }
}

// ---------------- flash attention ----------------
// grid (S/64, H, B); 4 waves, each owns 16 q-rows. Reads fused QKV (stride 3072).
__global__ __launch_bounds__(256, 2) void attn_kernel(
    const bf16* __restrict__ qkv, bf16* __restrict__ o) {
  const int S = 1024, QS = 3072, HD = 1024, KPAD = 960;
  const bf16* q = qkv;
  const bf16* k = qkv + 1024;
  const bf16* v = qkv + 2048;
  const int qt = blockIdx.x, h = blockIdx.y, b = blockIdx.z;
  const int t = threadIdx.x, lane = t & 63, w = t >> 6;
  const int l15 = lane & 15, l4 = lane >> 4;
  const int q0 = qt * 64;
  const int qw = q0 + w * 16;

  __shared__ __align__(16) bf16 Ks[32 * 64];
  __shared__ __align__(16) bf16 VT[64 * 32];
  __shared__ __align__(16) bf16 P[4][16 * 32];

  bf16x8 qf[2];
  {
    const bf16* qp = q + (size_t)(b * S + qw + l15) * QS + h * 64 + l4 * 8;
    qf[0] = *reinterpret_cast<const bf16x8*>(qp);
    qf[1] = *reinterpret_cast<const bf16x8*>(qp + 32);
  }

  f32x4 acc[4] = {};
  float mrow[4], lrow[4];
#pragma unroll
  for (int i = 0; i < 4; ++i) { mrow[i] = -1e30f; lrow[i] = 0.f; }

  const int kmaxa = q0 + 63, kmaxb = S - 65;
  const int kmax = kmaxa < kmaxb ? kmaxa : kmaxb;
  const int nt = (kmax >> 5) + 1;
  const int skey = t >> 3, sd = (t & 7) * 8;

  for (int kt = 0; kt < nt; ++kt) {
    const int kb = kt * 32;
    uint4 kv = *reinterpret_cast<const uint4*>(k + (size_t)(b * S + kb + skey) * QS + h * 64 + sd);
    uint4 vv = *reinterpret_cast<const uint4*>(v + (size_t)(b * S + kb + skey) * QS + h * 64 + sd);
    __syncthreads();
    *reinterpret_cast<uint4*>(&Ks[swz(skey, sd)]) = kv;
    union { uint4 u; bf16 e[8]; } vu; vu.u = vv;
#pragma unroll
    for (int j = 0; j < 8; ++j) {
      int d = sd + j;
      VT[d * 32 + (skey ^ ((d & 3) << 3))] = vu.e[j];
    }
    __syncthreads();

    f32x4 sc[2];
    __builtin_amdgcn_s_setprio(1);
#pragma unroll
    for (int cb = 0; cb < 2; ++cb) {
      int key = cb * 16 + l15;
      bf16x8 k0f = *reinterpret_cast<const bf16x8*>(&Ks[swz(key, l4 * 8)]);
      bf16x8 k1f = *reinterpret_cast<const bf16x8*>(&Ks[swz(key, 32 + l4 * 8)]);
      f32x4 z = {};
      z = __builtin_amdgcn_mfma_f32_16x16x32_bf16(qf[0], k0f, z, 0, 0, 0);
      z = __builtin_amdgcn_mfma_f32_16x16x32_bf16(qf[1], k1f, z, 0, 0, 0);
      sc[cb] = z;
    }
    __builtin_amdgcn_s_setprio(0);
#pragma unroll
    for (int cb = 0; cb < 2; ++cb) {
      int key = kb + cb * 16 + l15;
#pragma unroll
      for (int r = 0; r < 4; ++r) {
        int qrow = qw + l4 * 4 + r;
        float sv = sc[cb][r] * 0.125f;
        if (key > qrow || key >= KPAD) sv = -1e30f;
        sc[cb][r] = sv;
      }
    }
    float pr0[4], pr1[4];
#pragma unroll
    for (int r = 0; r < 4; ++r) {
      float mt = fmaxf(sc[0][r], sc[1][r]);
#pragma unroll
      for (int m = 8; m >= 1; m >>= 1) mt = fmaxf(mt, __shfl_xor(mt, m));
      float mn = fmaxf(mrow[r], mt);
      float alpha = __expf(mrow[r] - mn);
      float p0 = __expf(sc[0][r] - mn), p1 = __expf(sc[1][r] - mn);
      float rsum = p0 + p1;
#pragma unroll
      for (int m = 8; m >= 1; m >>= 1) rsum += __shfl_xor(rsum, m);
      lrow[r] = lrow[r] * alpha + rsum;
      mrow[r] = mn;
      pr0[r] = p0; pr1[r] = p1;
#pragma unroll
      for (int n = 0; n < 4; ++n) acc[n][r] *= alpha;
    }
#pragma unroll
    for (int r = 0; r < 4; ++r) {
      int rr = l4 * 4 + r;
      int c0 = l15, c1 = 16 + l15;
      P[w][rr * 32 + (c0 ^ ((rr & 3) << 3))] = __float2bfloat16(pr0[r]);
      P[w][rr * 32 + (c1 ^ ((rr & 3) << 3))] = __float2bfloat16(pr1[r]);
    }
    asm volatile("" ::: "memory");
    bf16x8 pf = *reinterpret_cast<const bf16x8*>(&P[w][l15 * 32 + ((l4 ^ (l15 & 3)) << 3)]);
    __builtin_amdgcn_s_setprio(1);
#pragma unroll
    for (int n = 0; n < 4; ++n) {
      int col = n * 16 + l15;
      bf16x8 vf = *reinterpret_cast<const bf16x8*>(&VT[col * 32 + ((l4 ^ (col & 3)) << 3)]);
      acc[n] = __builtin_amdgcn_mfma_f32_16x16x32_bf16(pf, vf, acc[n], 0, 0, 0);
    }
    __builtin_amdgcn_s_setprio(0);
  }
#pragma unroll
  for (int r = 0; r < 4; ++r) {
    float inv = 1.f / lrow[r];
    int qrow = qw + l4 * 4 + r;
#pragma unroll
    for (int n = 0; n < 4; ++n)
      o[(size_t)(b * S + qrow) * HD + h * 64 + n * 16 + l15] = __float2bfloat16(acc[n][r] * inv);
  }
}

// ---------------- launch ----------------
extern "C" void kernel_launch(void* const* d_in, const int* in_sizes, int n_in,
                              void* d_out, int out_size, void* d_ws, size_t ws_size,
                              hipStream_t stream) {
  const float* input = (const float*)d_in[0];
  const float* ln1g = (const float*)d_in[3];
  const float* ln1b = (const float*)d_in[4];
  const float* ln2g = (const float*)d_in[5];
  const float* ln2b = (const float*)d_in[6];
  const float* ln3g = (const float*)d_in[7];
  const float* ln3b = (const float*)d_in[8];
  const float* Wq = (const float*)d_in[9];  const float* bq = (const float*)d_in[10];
  const float* Wk = (const float*)d_in[11]; const float* bk = (const float*)d_in[12];
  const float* Wv = (const float*)d_in[13]; const float* bv = (const float*)d_in[14];
  const float* Wo = (const float*)d_in[15]; const float* bo = (const float*)d_in[16];
  const float* W1 = (const float*)d_in[17]; const float* b1 = (const float*)d_in[18];
  const float* W2 = (const float*)d_in[19]; const float* b2 = (const float*)d_in[20];

  const int M = 4096, D = 1024, F = 4096;
  char* p = (char*)d_ws;
  size_t off = 0;
  auto nxt = [&](size_t n) { char* r = p + off; off += n; return r; };
  bf16* WqkvT = (bf16*)nxt((size_t)3 * D * D * 2);   // rows: q 0..1023, k, v
  bf16* WoT = (bf16*)nxt((size_t)D * D * 2);
  bf16* W1T = (bf16*)nxt((size_t)F * D * 2);
  bf16* W2T = (bf16*)nxt((size_t)D * F * 2);
  float* bqkv = (float*)nxt(16384);
  float* xf  = (float*)nxt((size_t)M * D * 4);   // LN1 out (f32)
  float* aof = (float*)nxt((size_t)M * D * 4);   // attn proj out (f32)
  float* x2f = (float*)nxt((size_t)M * D * 4);   // x2 (f32)
  bf16* xb = (bf16*)nxt((size_t)M * D * 2);      // LN1 out bf16; reused as attn out
  bf16* qkv = (bf16*)nxt((size_t)M * 3 * D * 2); // fused qkv; reused as h
  bf16* gb = (bf16*)xf;   // gelu out [4096,4096] bf16 overlays xf+aof (dead by then)
  bf16* ab = xb;
  bf16* hb = qkv;

  dim3 tb(32, 8);
  transpose_cvt<<<dim3(D / 32, D / 32), tb, 0, stream>>>(Wq, WqkvT, D, D);
  transpose_cvt<<<dim3(D / 32, D / 32), tb, 0, stream>>>(Wk, WqkvT + (size_t)D * D, D, D);
  transpose_cvt<<<dim3(D / 32, D / 32), tb, 0, stream>>>(Wv, WqkvT + (size_t)2 * D * D, D, D);
  transpose_cvt<<<dim3(D / 32, D / 32), tb, 0, stream>>>(Wo, WoT, D, D);
  transpose_cvt<<<dim3(F / 32, D / 32), tb, 0, stream>>>(W1, W1T, D, F);
  transpose_cvt<<<dim3(D / 32, F / 32), tb, 0, stream>>>(W2, W2T, F, D);
  concat3<<<12, 256, 0, stream>>>(bq, bk, bv, bqkv);

  ln1_kernel<<<M, 256, 0, stream>>>(input, ln1g, ln1b, xf, xb);

  // fused QKV: [4096,3072]
  gemm_bt<128, 4, false, false, true><<<dim3(24, 32), 256, 0, stream>>>(
      xb, WqkvT, bqkv, nullptr, nullptr, qkv, M, 3 * D, D);

  attn_kernel<<<dim3(16, 16, 4), 256, 0, stream>>>(qkv, ab);

  gemm_bt<64, 2, false, false, false><<<dim3(16, 32), 256, 0, stream>>>(
      ab, WoT, bo, nullptr, aof, nullptr, M, D, D);

  ln23_kernel<<<M, 256, 0, stream>>>(xf, aof, ln2g, ln2b, ln3g, ln3b, x2f, hb);

  gemm_bt<128, 4, true, false, true><<<dim3(32, 32), 256, 0, stream>>>(
      hb, W1T, b1, nullptr, nullptr, gb, M, F, D);
  gemm_bt<64, 2, false, true, false><<<dim3(16, 32), 256, 0, stream>>>(
      gb, W2T, b2, x2f, (float*)d_out, nullptr, M, D, F);
}